// Round 20
// baseline (385.394 us; speedup 1.0000x reference)
//
#include <hip/hip_runtime.h>
#include <hip/hip_bf16.h>
#include <stdint.h>

#define T_ 128
#define B_ 8
#define V_ 32000
#define E_ 128
#define H_ 256
#define N_ 20
#define M_ 1024        // B*T rows
#define PIT 264        // LDS pitch (shorts) for K=256 B-tiles
#define PIT2 136       // LDS pitch (shorts) for K=128 B-tiles
#define NCH5 500       // V/64 stat chunks

typedef __attribute__((ext_vector_type(8))) short short8;
typedef __attribute__((ext_vector_type(4))) float f32x4;
typedef unsigned short ushort;

static __device__ __forceinline__ ushort f2bf_u(float f) {
  __hip_bfloat16 h = __float2bfloat16(f);
  return *reinterpret_cast<ushort*>(&h);
}

// ---------- fused prep: whb (blocks 0..31) + WiT (blocks 32..159) ----------
__global__ void prep_k(const float* __restrict__ Wh, uint4* __restrict__ whb4,
                       const float* __restrict__ Wi, float* __restrict__ WiT) {
  if (blockIdx.x < 32) {
    int idx = blockIdx.x*256 + threadIdx.x;   // 8192 entries
    int k8 = idx >> 8, i = idx & 255;
    const float* s = Wh + i*H_ + k8*8;
    uint4 o;
    o.x = (uint32_t)f2bf_u(s[0]) | ((uint32_t)f2bf_u(s[1]) << 16);
    o.y = (uint32_t)f2bf_u(s[2]) | ((uint32_t)f2bf_u(s[3]) << 16);
    o.z = (uint32_t)f2bf_u(s[4]) | ((uint32_t)f2bf_u(s[5]) << 16);
    o.w = (uint32_t)f2bf_u(s[6]) | ((uint32_t)f2bf_u(s[7]) << 16);
    whb4[idx] = o;
  } else {
    int idx = (blockIdx.x - 32)*256 + threadIdx.x;
    if (idx < H_*E_) {
      int i = idx >> 7, e = idx & (E_-1);
      WiT[e*H_ + i] = Wi[idx];
    }
  }
}

// ---------- RI[r][i] = (l2norm(emb[x_ids]) @ W_i.T)[i] ----------
__global__ __launch_bounds__(256) void ri_k(const int* __restrict__ x_ids,
    const float* __restrict__ emb, const float* __restrict__ WiT,
    float* __restrict__ RI)
{
  __shared__ float xn[E_];
  __shared__ float red[2];
  int r = blockIdx.x, tid = threadIdx.x;
  int id = x_ids[r];
  float v = 0.f;
  if (tid < E_) v = emb[id*E_ + tid];
  float ss = v*v;
  if (tid < E_) {
    #pragma unroll
    for (int off = 32; off >= 1; off >>= 1) ss += __shfl_xor(ss, off);
    if ((tid & 63) == 0) red[tid >> 6] = ss;
  }
  __syncthreads();
  float inv = 1.f / fmaxf(sqrtf(red[0] + red[1]), 1e-12f);
  if (tid < E_) xn[tid] = v*inv;
  __syncthreads();
  float s = 0.f;
  for (int e = 0; e < E_; ++e) s += xn[e]*WiT[e*H_ + tid];
  RI[r*H_ + tid] = s;
}

// ---------- h-chain (round-12 structure) + fused foldfc/embn on idle CUs ----------
__global__ __launch_bounds__(1024) void chain_k(
    const uint4* __restrict__ whb4, const float* __restrict__ RI,
    float* __restrict__ HMf, ushort* __restrict__ HMb,
    const float* __restrict__ Wfc, const float* __restrict__ emb,
    ushort* __restrict__ Wfcb, ushort* __restrict__ embnb)
{
  __shared__ uint4 wlds[32*256];                  // 128 KB, [k8][i]
  __shared__ __align__(16) float hbuf[2][H_];
  __shared__ float hred[3][H_];
  const int tid = threadIdx.x;

  if (blockIdx.x >= B_) {                         // ---- pre-work blocks ----
    const int nb = gridDim.x - B_;
    const int bx = blockIdx.x - B_;
    for (long idx = (long)bx*1024 + tid; idx < (long)V_*H_; idx += (long)nb*1024) {
      int n = idx >> 8, k = idx & 255;
      Wfcb[idx] = f2bf_u(Wfc[(size_t)n*2*H_ + k] + Wfc[(size_t)n*2*H_ + H_ + k]);
    }
    const int wv = tid >> 6, l = tid & 63;
    for (int v = bx*16 + wv; v < V_; v += nb*16) {
      float e0 = emb[(size_t)v*E_ + l];
      float e1 = emb[(size_t)v*E_ + 64 + l];
      float ss = e0*e0 + e1*e1;
      #pragma unroll
      for (int off = 32; off >= 1; off >>= 1) ss += __shfl_xor(ss, off);
      float inv = 1.f / fmaxf(sqrtf(ss), 1e-8f);
      embnb[(size_t)v*E_ + l]      = f2bf_u(e0*inv);
      embnb[(size_t)v*E_ + 64 + l] = f2bf_u(e1*inv);
    }
    return;
  }

  const int b = blockIdx.x;
  const int q = tid >> 8, i = tid & 255;

  for (int m = tid; m < 32*256; m += 1024) wlds[m] = whb4[m];
  if (q == 0) hbuf[0][i] = 0.f;
  __syncthreads();
  float ri_c = (q == 0) ? RI[(size_t)b*T_*H_ + i] : 0.f;

  for (int t = 0; t < T_; ++t) {
    const int r = b*T_ + t;
    float ri_n = 0.f;
    if (q == 0 && t+1 < T_) ri_n = RI[(size_t)(r+1)*H_ + i];  // prefetch
    const float4* h4 = reinterpret_cast<const float4*>(hbuf[t & 1]);
    float p0 = 0.f, p1 = 0.f, p2 = 0.f, p3 = 0.f;
    #pragma unroll
    for (int j = 0; j < 8; ++j) {
      uint4 w = wlds[(q*8 + j)*256 + i];          // lane-contiguous b128
      float4 ha = h4[q*16 + 2*j];                 // wave-uniform broadcast
      float4 hb = h4[q*16 + 2*j + 1];
      p0 += __uint_as_float(w.x << 16)*ha.x + __uint_as_float(w.x & 0xffff0000u)*ha.y;
      p1 += __uint_as_float(w.y << 16)*ha.z + __uint_as_float(w.y & 0xffff0000u)*ha.w;
      p2 += __uint_as_float(w.z << 16)*hb.x + __uint_as_float(w.z & 0xffff0000u)*hb.y;
      p3 += __uint_as_float(w.w << 16)*hb.z + __uint_as_float(w.w & 0xffff0000u)*hb.w;
    }
    float p = (p0 + p1) + (p2 + p3);
    if (q) hred[q-1][i] = p;
    __syncthreads();
    if (q == 0) {
      float s = ri_c + p + hred[0][i] + hred[1][i] + hred[2][i];
      float hn = tanhf(s);
      hbuf[(t+1) & 1][i] = hn;                    // ping-pong: no WAR
      float hm = 1.f - fmaxf(hn, 0.f);
      HMf[(size_t)r*H_ + i] = hm;
      HMb[(size_t)r*H_ + i] = f2bf_u(hm);
    }
    ri_c = ri_n;
    __syncthreads();
  }
}

// ========== pass A: M=512 x N=64 tiles (8 waves), B staged once per block ==========
// grid (500, 3): y==0,x<8 = fused stack path; y=1..2 tiles, Rb=(y-1)*512.
__global__ __launch_bounds__(512) void stats7_k(const ushort* __restrict__ HMb,
    const ushort* __restrict__ Wfcb, const float* __restrict__ HMf,
    const float* __restrict__ W_ops, const float* __restrict__ W_ch,
    const float* __restrict__ sharp, const int* __restrict__ x_ids,
    const float* __restrict__ emb,
    float* __restrict__ SS, float* __restrict__ CH, float* __restrict__ PV,
    ushort* __restrict__ PVNb)
{
  __shared__ __align__(16) char smem[64*PIT*2];   // 33.8 KB union
  const int tid = threadIdx.x;
  const int wave = tid >> 6, lane = tid & 63;
  const int lr = lane & 15, g = lane >> 4;

  if (blockIdx.y == 0) {                          // ---- fused stack path ----
    if (blockIdx.x >= B_) return;
    float*  ops_l = (float*)smem;                 // T_*4 = 2048B
    float2* pw_l  = (float2*)(smem + 2048);       // T_*N_ = 20480B
    int*    ids_l = (int*)(smem + 2048 + 20480);  // T_ = 512B
    const int b = blockIdx.x;
    float wo[5][4];
    #pragma unroll
    for (int k = 0; k < 3; ++k)
      #pragma unroll
      for (int j = 0; j < 4; ++j)
        wo[k][j] = W_ops[k*2*H_ + 4*lane + j] + W_ops[k*2*H_ + H_ + 4*lane + j];
    #pragma unroll
    for (int k = 0; k < 2; ++k)
      #pragma unroll
      for (int j = 0; j < 4; ++j)
        wo[3+k][j] = W_ch[k*2*H_ + 4*lane + j] + W_ch[k*2*H_ + H_ + 4*lane + j];
    if (tid < T_) ids_l[tid] = x_ids[b*T_ + tid];
    int rend = wave*32 + 32; if (rend > T_) rend = T_;
    for (int rl = wave*32; rl < rend; ++rl) {     // phase A: gates (waves 0-3)
      int R = b*T_ + rl;
      float4 hm4 = reinterpret_cast<const float4*>(HMf + (size_t)R*H_)[lane];
      float d0 = hm4.x*wo[0][0] + hm4.y*wo[0][1] + hm4.z*wo[0][2] + hm4.w*wo[0][3];
      float d1 = hm4.x*wo[1][0] + hm4.y*wo[1][1] + hm4.z*wo[1][2] + hm4.w*wo[1][3];
      float d2 = hm4.x*wo[2][0] + hm4.y*wo[2][1] + hm4.z*wo[2][2] + hm4.w*wo[2][3];
      float d3 = hm4.x*wo[3][0] + hm4.y*wo[3][1] + hm4.z*wo[3][2] + hm4.w*wo[3][3];
      float d4 = hm4.x*wo[4][0] + hm4.y*wo[4][1] + hm4.z*wo[4][2] + hm4.w*wo[4][3];
      #pragma unroll
      for (int off = 32; off >= 1; off >>= 1) {
        d0 += __shfl_xor(d0, off); d1 += __shfl_xor(d1, off); d2 += __shfl_xor(d2, off);
        d3 += __shfl_xor(d3, off); d4 += __shfl_xor(d4, off);
      }
      if (lane == 0) {
        float mx = fmaxf(d0, fmaxf(d1, d2));
        float e0 = expf(d0-mx), e1 = expf(d1-mx), e2 = expf(d2-mx);
        float oi = 1.f/(e0+e1+e2);
        ops_l[rl*4+0] = e0*oi; ops_l[rl*4+1] = e1*oi; ops_l[rl*4+2] = e2*oi;
        float cm = fmaxf(d3, d4);
        float f0 = expf(d3-cm), f1 = expf(d4-cm);
        float ci = 1.f/(f0+f1);
        CH[R*2] = f0*ci; CH[R*2+1] = f1*ci;
      }
    }
    __syncthreads();
    if (tid < 64) {                               // phase B: serial ptr recurrence
      const float sh = sharp[0];
      float ptr = (tid == 0) ? 1.f : 0.f;
      const int lp = (tid + N_ - 1) % N_, ln = (tid + 1) % N_;
      for (int t = 0; t < T_; ++t) {
        float push = ops_l[t*4+0], pop = ops_l[t*4+1], nop = ops_l[t*4+2];
        float pp = __shfl(ptr, lp);
        float po = __shfl(ptr, ln);
        float wgt = push*pp;
        float raw = wgt + pop*po + nop*ptr;
        float np = 0.f;
        if (tid < N_) np = exp2f(sh * log2f(fmaxf(raw, 1e-8f)));
        float ssum = np;
        #pragma unroll
        for (int off = 1; off < 32; off <<= 1) ssum += __shfl_xor(ssum, off);
        if (tid < N_) {
          pw_l[t*N_ + tid] = make_float2(ptr, wgt);
          ptr = np / ssum;
        }
      }
    }
    __syncthreads();
    if (tid < E_) {                               // phase C: stack + pop_val
      const int e = tid;
      float stck[N_];
      #pragma unroll
      for (int n = 0; n < N_; ++n) stck[n] = 0.001f;
      float xi_c = emb[(size_t)ids_l[0]*E_ + e];
      for (int t = 0; t < T_; ++t) {
        float xi_n = (t+1 < T_) ? emb[(size_t)ids_l[t+1]*E_ + e] : 0.f;
        float pv = 0.f;
        #pragma unroll
        for (int n = 0; n < N_; ++n) {
          float2 pw = pw_l[t*N_ + n];
          pv += pw.x * stck[n];
          stck[n] += pw.y * (xi_c - stck[n]);
        }
        PV[(size_t)(b*T_ + t)*E_ + e] = pv;
        xi_c = xi_n;
      }
    }
    __threadfence_block();
    __syncthreads();
    for (int rl = wave*32; rl < rend; ++rl) {     // phase D: pv normalize
      int R = b*T_ + rl;
      float a = PV[(size_t)R*E_ + lane];
      float c = PV[(size_t)R*E_ + 64 + lane];
      float ss = a*a + c*c;
      #pragma unroll
      for (int off = 32; off >= 1; off >>= 1) ss += __shfl_xor(ss, off);
      float inv = 1.f / fmaxf(sqrtf(ss), 1e-8f);
      PVNb[(size_t)R*E_ + lane]      = f2bf_u(a*inv);
      PVNb[(size_t)R*E_ + 64 + lane] = f2bf_u(c*inv);
    }
    return;
  }

  // ---- tile path: 512(M) x 64(N), 8 waves x 4 m-tiles, A per-ks from global ----
  ushort* Bs = (ushort*)smem;
  const int Cb = blockIdx.x*64;
  {
    const uint4* srcB = (const uint4*)(Wfcb + (size_t)Cb*H_);
    #pragma unroll
    for (int it = 0; it < 4; ++it) {
      int idx = it*512 + tid, row = idx >> 5, c = idx & 31;
      *(uint4*)&Bs[row*PIT + c*8] = srcB[row*32 + c];
    }
  }
  const int Rw = (blockIdx.y - 1)*512 + wave*64;
  __syncthreads();
  f32x4 acc[4][4] = {};
  #pragma unroll
  for (int ks = 0; ks < 8; ++ks) {
    short8 a0 = *(const short8*)(HMb + (size_t)(Rw + 0*16 + lr)*H_ + ks*32 + g*8);
    short8 a1 = *(const short8*)(HMb + (size_t)(Rw + 1*16 + lr)*H_ + ks*32 + g*8);
    short8 a2 = *(const short8*)(HMb + (size_t)(Rw + 2*16 + lr)*H_ + ks*32 + g*8);
    short8 a3 = *(const short8*)(HMb + (size_t)(Rw + 3*16 + lr)*H_ + ks*32 + g*8);
    short8 b0 = *(const short8*)(&Bs[(0*16 + lr)*PIT + ks*32 + g*8]);
    short8 b1 = *(const short8*)(&Bs[(1*16 + lr)*PIT + ks*32 + g*8]);
    short8 b2 = *(const short8*)(&Bs[(2*16 + lr)*PIT + ks*32 + g*8]);
    short8 b3 = *(const short8*)(&Bs[(3*16 + lr)*PIT + ks*32 + g*8]);
    #define MF(mi, av) \
      acc[mi][0] = __builtin_amdgcn_mfma_f32_16x16x32_bf16(av, b0, acc[mi][0], 0, 0, 0); \
      acc[mi][1] = __builtin_amdgcn_mfma_f32_16x16x32_bf16(av, b1, acc[mi][1], 0, 0, 0); \
      acc[mi][2] = __builtin_amdgcn_mfma_f32_16x16x32_bf16(av, b2, acc[mi][2], 0, 0, 0); \
      acc[mi][3] = __builtin_amdgcn_mfma_f32_16x16x32_bf16(av, b3, acc[mi][3], 0, 0, 0);
    MF(0, a0) MF(1, a1) MF(2, a2) MF(3, a3)
    #undef MF
  }
  #pragma unroll
  for (int mi = 0; mi < 4; ++mi)
    #pragma unroll
    for (int r = 0; r < 4; ++r) {
      float s = expf(acc[mi][0][r]) + expf(acc[mi][1][r])
              + expf(acc[mi][2][r]) + expf(acc[mi][3][r]);
      #pragma unroll
      for (int off = 1; off < 16; off <<= 1) s += __shfl_xor(s, off);
      if (lr == 0) SS[(size_t)blockIdx.x*M_ + (Rw + mi*16 + g*4 + r)] = s;
    }
}

// ---------- combine chunk sums (SS transposed [chunk][row]) ----------
__global__ void reduce5_k(const float* __restrict__ SS, float* __restrict__ MS) {
  int row = blockIdx.x, l = threadIdx.x;  // 64 threads
  float s = 0.f;
  for (int c = l; c < NCH5; c += 64) s += SS[(size_t)c*M_ + row];
  #pragma unroll
  for (int off = 32; off >= 1; off >>= 1) s += __shfl_xor(s, off);
  if (l == 0) MS[row] = 1.f/s;
}

// ========== pass B: M=512 x N=64 (8 waves), logits recompute + syntactic ==========
__global__ __launch_bounds__(512) void final7_k(const ushort* __restrict__ HMb,
    const ushort* __restrict__ Wfcb, const ushort* __restrict__ PVNb,
    const ushort* __restrict__ embnb, const float* __restrict__ MS,
    const float* __restrict__ CH, float* __restrict__ out)
{
  __shared__ __align__(16) ushort Bs[64*PIT];     // 33.8 KB
  const int tid = threadIdx.x;
  const int Cb = blockIdx.x*64;
  const int wave = tid >> 6, lane = tid & 63;
  const int lr = lane & 15, g = lane >> 4;
  const int Rw = blockIdx.y*512 + wave*64;

  // logits (identical op sequence to stats7 -> bitwise-same)
  {
    const uint4* srcB = (const uint4*)(Wfcb + (size_t)Cb*H_);
    #pragma unroll
    for (int it = 0; it < 4; ++it) {
      int idx = it*512 + tid, row = idx >> 5, c = idx & 31;
      *(uint4*)&Bs[row*PIT + c*8] = srcB[row*32 + c];
    }
  }
  __syncthreads();
  f32x4 accL[4][4] = {};
  #pragma unroll
  for (int ks = 0; ks < 8; ++ks) {
    short8 a0 = *(const short8*)(HMb + (size_t)(Rw + 0*16 + lr)*H_ + ks*32 + g*8);
    short8 a1 = *(const short8*)(HMb + (size_t)(Rw + 1*16 + lr)*H_ + ks*32 + g*8);
    short8 a2 = *(const short8*)(HMb + (size_t)(Rw + 2*16 + lr)*H_ + ks*32 + g*8);
    short8 a3 = *(const short8*)(HMb + (size_t)(Rw + 3*16 + lr)*H_ + ks*32 + g*8);
    short8 b0 = *(const short8*)(&Bs[(0*16 + lr)*PIT + ks*32 + g*8]);
    short8 b1 = *(const short8*)(&Bs[(1*16 + lr)*PIT + ks*32 + g*8]);
    short8 b2 = *(const short8*)(&Bs[(2*16 + lr)*PIT + ks*32 + g*8]);
    short8 b3 = *(const short8*)(&Bs[(3*16 + lr)*PIT + ks*32 + g*8]);
    #define MFL(mi, av) \
      accL[mi][0] = __builtin_amdgcn_mfma_f32_16x16x32_bf16(av, b0, accL[mi][0], 0, 0, 0); \
      accL[mi][1] = __builtin_amdgcn_mfma_f32_16x16x32_bf16(av, b1, accL[mi][1], 0, 0, 0); \
      accL[mi][2] = __builtin_amdgcn_mfma_f32_16x16x32_bf16(av, b2, accL[mi][2], 0, 0, 0); \
      accL[mi][3] = __builtin_amdgcn_mfma_f32_16x16x32_bf16(av, b3, accL[mi][3], 0, 0, 0);
    MFL(0, a0) MFL(1, a1) MFL(2, a2) MFL(3, a3)
    #undef MFL
  }
  __syncthreads();   // all waves done reading logits B

  // syntactic K=128
  {
    const uint4* srcB = (const uint4*)(embnb + (size_t)Cb*E_);
    #pragma unroll
    for (int it = 0; it < 2; ++it) {
      int idx = it*512 + tid, row = idx >> 4, c = idx & 15;
      *(uint4*)&Bs[row*PIT2 + c*8] = srcB[row*16 + c];
    }
  }
  __syncthreads();
  f32x4 accS[4][4] = {};
  #pragma unroll
  for (int ks = 0; ks < 4; ++ks) {
    short8 a0 = *(const short8*)(PVNb + (size_t)(Rw + 0*16 + lr)*E_ + ks*32 + g*8);
    short8 a1 = *(const short8*)(PVNb + (size_t)(Rw + 1*16 + lr)*E_ + ks*32 + g*8);
    short8 a2 = *(const short8*)(PVNb + (size_t)(Rw + 2*16 + lr)*E_ + ks*32 + g*8);
    short8 a3 = *(const short8*)(PVNb + (size_t)(Rw + 3*16 + lr)*E_ + ks*32 + g*8);
    short8 b0 = *(const short8*)(&Bs[(0*16 + lr)*PIT2 + ks*32 + g*8]);
    short8 b1 = *(const short8*)(&Bs[(1*16 + lr)*PIT2 + ks*32 + g*8]);
    short8 b2 = *(const short8*)(&Bs[(2*16 + lr)*PIT2 + ks*32 + g*8]);
    short8 b3 = *(const short8*)(&Bs[(3*16 + lr)*PIT2 + ks*32 + g*8]);
    #define MFS(mi, av) \
      accS[mi][0] = __builtin_amdgcn_mfma_f32_16x16x32_bf16(av, b0, accS[mi][0], 0, 0, 0); \
      accS[mi][1] = __builtin_amdgcn_mfma_f32_16x16x32_bf16(av, b1, accS[mi][1], 0, 0, 0); \
      accS[mi][2] = __builtin_amdgcn_mfma_f32_16x16x32_bf16(av, b2, accS[mi][2], 0, 0, 0); \
      accS[mi][3] = __builtin_amdgcn_mfma_f32_16x16x32_bf16(av, b3, accS[mi][3], 0, 0, 0);
    MFS(0, a0) MFS(1, a1) MFS(2, a2) MFS(3, a3)
    #undef MFS
  }

  #pragma unroll
  for (int mi = 0; mi < 4; ++mi)
    #pragma unroll
    for (int r = 0; r < 4; ++r) {
      int row = Rw + mi*16 + g*4 + r;
      float Si = MS[row];
      float c0 = CH[row*2], c1 = CH[row*2+1];
      size_t base = (size_t)row*V_ + Cb + lr;
      #pragma unroll
      for (int nj = 0; nj < 4; ++nj)
        out[base + nj*16] = c0*expf(accL[mi][nj][r])*Si + c1*accS[mi][nj][r];
    }
}

extern "C" void kernel_launch(void* const* d_in, const int* in_sizes, int n_in,
                              void* d_out, int out_size, void* d_ws, size_t ws_size,
                              hipStream_t stream) {
  const int*   x_ids = (const int*)d_in[0];
  const float* emb   = (const float*)d_in[1];
  const float* W_i   = (const float*)d_in[2];
  const float* W_h   = (const float*)d_in[3];
  const float* W_fc  = (const float*)d_in[4];
  const float* W_ops = (const float*)d_in[5];
  const float* W_ch  = (const float*)d_in[6];
  const float* sharp = (const float*)d_in[7];
  float* out = (float*)d_out;

  float* ws    = (float*)d_ws;             // ~31 MB total
  uint4*  whb4 = (uint4*)ws;               // 8192 uint4 = 32768 floats
  float*  WiT  = ws + 65536;               // 32768
  float*  RI   = WiT + 32768;              // 262144
  float*  CH   = RI + 262144;              // 2048
  float*  MS   = CH + 2048;                // 1024
  float*  SS   = MS + 1024;                // 512,000 (transposed [chunk][row])
  float*  HMf  = SS + 512000;              // 262144
  float*  PV   = HMf + 262144;             // 131072
  float*  fend = PV + 131072;
  ushort* HMb   = (ushort*)fend;           // 262144 shorts
  ushort* PVNb  = HMb + 262144;            // 131072
  ushort* Wfcb  = PVNb + 131072;           // 8,192,000
  ushort* embnb = Wfcb + 8192000;          // 4,096,000

  prep_k <<<160, 256, 0, stream>>>(W_h, whb4, W_i, WiT);
  ri_k   <<<M_, 256, 0, stream>>>(x_ids, emb, WiT, RI);
  chain_k<<<248, 1024, 0, stream>>>(whb4, RI, HMf, HMb, W_fc, emb, Wfcb, embnb);
  stats7_k<<<dim3(NCH5, 3), 512, 0, stream>>>(HMb, Wfcb, HMf, W_ops, W_ch, sharp,
                                              x_ids, emb, SS, CH, PV, PVNb);
  reduce5_k<<<M_, 64, 0, stream>>>(SS, MS);
  final7_k<<<dim3(NCH5, M_/512), 512, 0, stream>>>(HMb, Wfcb, PVNb, embnb, MS, CH, out);
}

// Round 21
// 380.350 us; speedup vs baseline: 1.0133x; 1.0133x over previous
//
#include <hip/hip_runtime.h>
#include <hip/hip_bf16.h>
#include <stdint.h>

#define T_ 128
#define B_ 8
#define V_ 32000
#define E_ 128
#define H_ 256
#define N_ 20
#define M_ 1024        // B*T rows
#define PIT 264        // LDS pitch (shorts) for K=256 B-tiles
#define PIT2 136       // LDS pitch (shorts) for K=128 B-tiles
#define NCH5 500       // V/64 stat chunks

typedef __attribute__((ext_vector_type(8))) short short8;
typedef __attribute__((ext_vector_type(4))) float f32x4;
typedef unsigned short ushort;

static __device__ __forceinline__ ushort f2bf_u(float f) {
  __hip_bfloat16 h = __float2bfloat16(f);
  return *reinterpret_cast<ushort*>(&h);
}

// ---------- fused prep: whb (blocks 0..31) + WiT (blocks 32..159) ----------
__global__ void prep_k(const float* __restrict__ Wh, uint4* __restrict__ whb4,
                       const float* __restrict__ Wi, float* __restrict__ WiT) {
  if (blockIdx.x < 32) {
    int idx = blockIdx.x*256 + threadIdx.x;   // 8192 entries
    int k8 = idx >> 8, i = idx & 255;
    const float* s = Wh + i*H_ + k8*8;
    uint4 o;
    o.x = (uint32_t)f2bf_u(s[0]) | ((uint32_t)f2bf_u(s[1]) << 16);
    o.y = (uint32_t)f2bf_u(s[2]) | ((uint32_t)f2bf_u(s[3]) << 16);
    o.z = (uint32_t)f2bf_u(s[4]) | ((uint32_t)f2bf_u(s[5]) << 16);
    o.w = (uint32_t)f2bf_u(s[6]) | ((uint32_t)f2bf_u(s[7]) << 16);
    whb4[idx] = o;
  } else {
    int idx = (blockIdx.x - 32)*256 + threadIdx.x;
    if (idx < H_*E_) {
      int i = idx >> 7, e = idx & (E_-1);
      WiT[e*H_ + i] = Wi[idx];
    }
  }
}

// ---------- RI[r][i] = (l2norm(emb[x_ids]) @ W_i.T)[i] ----------
__global__ __launch_bounds__(256) void ri_k(const int* __restrict__ x_ids,
    const float* __restrict__ emb, const float* __restrict__ WiT,
    float* __restrict__ RI)
{
  __shared__ float xn[E_];
  __shared__ float red[2];
  int r = blockIdx.x, tid = threadIdx.x;
  int id = x_ids[r];
  float v = 0.f;
  if (tid < E_) v = emb[id*E_ + tid];
  float ss = v*v;
  if (tid < E_) {
    #pragma unroll
    for (int off = 32; off >= 1; off >>= 1) ss += __shfl_xor(ss, off);
    if ((tid & 63) == 0) red[tid >> 6] = ss;
  }
  __syncthreads();
  float inv = 1.f / fmaxf(sqrtf(red[0] + red[1]), 1e-12f);
  if (tid < E_) xn[tid] = v*inv;
  __syncthreads();
  float s = 0.f;
  for (int e = 0; e < E_; ++e) s += xn[e]*WiT[e*H_ + tid];
  RI[r*H_ + tid] = s;
}

// ---------- h-chain (round-12 structure) + fused foldfc/embn on idle CUs ----------
// blocks 0..7: chain (W_h bf16 in LDS, 1024 thr, fp32 h).
// blocks 8..: grid-stride foldfc (Wfcb) and embn (embnb) pre-work, hidden under chain.
__global__ __launch_bounds__(1024) void chain_k(
    const uint4* __restrict__ whb4, const float* __restrict__ RI,
    float* __restrict__ HMf, ushort* __restrict__ HMb,
    const float* __restrict__ Wfc, const float* __restrict__ emb,
    ushort* __restrict__ Wfcb, ushort* __restrict__ embnb)
{
  __shared__ uint4 wlds[32*256];                  // 128 KB, [k8][i]
  __shared__ __align__(16) float hbuf[2][H_];
  __shared__ float hred[3][H_];
  const int tid = threadIdx.x;

  if (blockIdx.x >= B_) {                         // ---- pre-work blocks ----
    const int nb = gridDim.x - B_;
    const int bx = blockIdx.x - B_;
    for (long idx = (long)bx*1024 + tid; idx < (long)V_*H_; idx += (long)nb*1024) {
      int n = idx >> 8, k = idx & 255;
      Wfcb[idx] = f2bf_u(Wfc[(size_t)n*2*H_ + k] + Wfc[(size_t)n*2*H_ + H_ + k]);
    }
    const int wv = tid >> 6, l = tid & 63;
    for (int v = bx*16 + wv; v < V_; v += nb*16) {
      float e0 = emb[(size_t)v*E_ + l];
      float e1 = emb[(size_t)v*E_ + 64 + l];
      float ss = e0*e0 + e1*e1;
      #pragma unroll
      for (int off = 32; off >= 1; off >>= 1) ss += __shfl_xor(ss, off);
      float inv = 1.f / fmaxf(sqrtf(ss), 1e-8f);
      embnb[(size_t)v*E_ + l]      = f2bf_u(e0*inv);
      embnb[(size_t)v*E_ + 64 + l] = f2bf_u(e1*inv);
    }
    return;
  }

  const int b = blockIdx.x;
  const int q = tid >> 8, i = tid & 255;

  for (int m = tid; m < 32*256; m += 1024) wlds[m] = whb4[m];
  if (q == 0) hbuf[0][i] = 0.f;
  __syncthreads();
  float ri_c = (q == 0) ? RI[(size_t)b*T_*H_ + i] : 0.f;

  for (int t = 0; t < T_; ++t) {
    const int r = b*T_ + t;
    float ri_n = 0.f;
    if (q == 0 && t+1 < T_) ri_n = RI[(size_t)(r+1)*H_ + i];  // prefetch
    const float4* h4 = reinterpret_cast<const float4*>(hbuf[t & 1]);
    float p0 = 0.f, p1 = 0.f, p2 = 0.f, p3 = 0.f;
    #pragma unroll
    for (int j = 0; j < 8; ++j) {
      uint4 w = wlds[(q*8 + j)*256 + i];          // lane-contiguous b128
      float4 ha = h4[q*16 + 2*j];                 // wave-uniform broadcast
      float4 hb = h4[q*16 + 2*j + 1];
      p0 += __uint_as_float(w.x << 16)*ha.x + __uint_as_float(w.x & 0xffff0000u)*ha.y;
      p1 += __uint_as_float(w.y << 16)*ha.z + __uint_as_float(w.y & 0xffff0000u)*ha.w;
      p2 += __uint_as_float(w.z << 16)*hb.x + __uint_as_float(w.z & 0xffff0000u)*hb.y;
      p3 += __uint_as_float(w.w << 16)*hb.z + __uint_as_float(w.w & 0xffff0000u)*hb.w;
    }
    float p = (p0 + p1) + (p2 + p3);
    if (q) hred[q-1][i] = p;
    __syncthreads();
    if (q == 0) {
      float s = ri_c + p + hred[0][i] + hred[1][i] + hred[2][i];
      float hn = tanhf(s);
      hbuf[(t+1) & 1][i] = hn;                    // ping-pong: no WAR
      float hm = 1.f - fmaxf(hn, 0.f);
      HMf[(size_t)r*H_ + i] = hm;
      HMb[(size_t)r*H_ + i] = f2bf_u(hm);
    }
    ri_c = ri_n;
    __syncthreads();
  }
}

// ========== pass A: M=256 x N=64 tiles, 4 m-tiles/wave, B in LDS ==========
// grid (500, 5): y==0,x<8 = fused stack path; y=1..4 tiles, Rb=(y-1)*256.
__global__ __launch_bounds__(256) void stats6_k(const ushort* __restrict__ HMb,
    const ushort* __restrict__ Wfcb, const float* __restrict__ HMf,
    const float* __restrict__ W_ops, const float* __restrict__ W_ch,
    const float* __restrict__ sharp, const int* __restrict__ x_ids,
    const float* __restrict__ emb,
    float* __restrict__ SS, float* __restrict__ CH, float* __restrict__ PV,
    ushort* __restrict__ PVNb)
{
  __shared__ __align__(16) char smem[64*PIT*2];   // 33.8 KB union
  const int tid = threadIdx.x;
  const int wave = tid >> 6, lane = tid & 63;
  const int lr = lane & 15, g = lane >> 4;

  if (blockIdx.y == 0) {                          // ---- fused stack path ----
    if (blockIdx.x >= B_) return;
    float*  ops_l = (float*)smem;                 // T_*4 = 2048B
    float2* pw_l  = (float2*)(smem + 2048);       // T_*N_ = 20480B
    int*    ids_l = (int*)(smem + 2048 + 20480);  // T_ = 512B
    const int b = blockIdx.x;
    float wo[5][4];
    #pragma unroll
    for (int k = 0; k < 3; ++k)
      #pragma unroll
      for (int j = 0; j < 4; ++j)
        wo[k][j] = W_ops[k*2*H_ + 4*lane + j] + W_ops[k*2*H_ + H_ + 4*lane + j];
    #pragma unroll
    for (int k = 0; k < 2; ++k)
      #pragma unroll
      for (int j = 0; j < 4; ++j)
        wo[3+k][j] = W_ch[k*2*H_ + 4*lane + j] + W_ch[k*2*H_ + H_ + 4*lane + j];
    if (tid < T_) ids_l[tid] = x_ids[b*T_ + tid];
    for (int rl = wave*32; rl < wave*32 + 32; ++rl) {   // phase A: gates
      int R = b*T_ + rl;
      float4 hm4 = reinterpret_cast<const float4*>(HMf + (size_t)R*H_)[lane];
      float d0 = hm4.x*wo[0][0] + hm4.y*wo[0][1] + hm4.z*wo[0][2] + hm4.w*wo[0][3];
      float d1 = hm4.x*wo[1][0] + hm4.y*wo[1][1] + hm4.z*wo[1][2] + hm4.w*wo[1][3];
      float d2 = hm4.x*wo[2][0] + hm4.y*wo[2][1] + hm4.z*wo[2][2] + hm4.w*wo[2][3];
      float d3 = hm4.x*wo[3][0] + hm4.y*wo[3][1] + hm4.z*wo[3][2] + hm4.w*wo[3][3];
      float d4 = hm4.x*wo[4][0] + hm4.y*wo[4][1] + hm4.z*wo[4][2] + hm4.w*wo[4][3];
      #pragma unroll
      for (int off = 32; off >= 1; off >>= 1) {
        d0 += __shfl_xor(d0, off); d1 += __shfl_xor(d1, off); d2 += __shfl_xor(d2, off);
        d3 += __shfl_xor(d3, off); d4 += __shfl_xor(d4, off);
      }
      if (lane == 0) {
        float mx = fmaxf(d0, fmaxf(d1, d2));
        float e0 = expf(d0-mx), e1 = expf(d1-mx), e2 = expf(d2-mx);
        float oi = 1.f/(e0+e1+e2);
        ops_l[rl*4+0] = e0*oi; ops_l[rl*4+1] = e1*oi; ops_l[rl*4+2] = e2*oi;
        float cm = fmaxf(d3, d4);
        float f0 = expf(d3-cm), f1 = expf(d4-cm);
        float ci = 1.f/(f0+f1);
        CH[R*2] = f0*ci; CH[R*2+1] = f1*ci;
      }
    }
    __syncthreads();
    if (tid < 64) {                               // phase B: serial ptr recurrence
      const float sh = sharp[0];
      float ptr = (tid == 0) ? 1.f : 0.f;
      const int lp = (tid + N_ - 1) % N_, ln = (tid + 1) % N_;
      for (int t = 0; t < T_; ++t) {
        float push = ops_l[t*4+0], pop = ops_l[t*4+1], nop = ops_l[t*4+2];
        float pp = __shfl(ptr, lp);
        float po = __shfl(ptr, ln);
        float wgt = push*pp;
        float raw = wgt + pop*po + nop*ptr;
        float np = 0.f;
        if (tid < N_) np = exp2f(sh * log2f(fmaxf(raw, 1e-8f)));
        float ssum = np;
        #pragma unroll
        for (int off = 1; off < 32; off <<= 1) ssum += __shfl_xor(ssum, off);
        if (tid < N_) {
          pw_l[t*N_ + tid] = make_float2(ptr, wgt);
          ptr = np / ssum;
        }
      }
    }
    __syncthreads();
    if (tid < E_) {                               // phase C: stack + pop_val
      const int e = tid;
      float stck[N_];
      #pragma unroll
      for (int n = 0; n < N_; ++n) stck[n] = 0.001f;
      float xi_c = emb[(size_t)ids_l[0]*E_ + e];
      for (int t = 0; t < T_; ++t) {
        float xi_n = (t+1 < T_) ? emb[(size_t)ids_l[t+1]*E_ + e] : 0.f;
        float pv = 0.f;
        #pragma unroll
        for (int n = 0; n < N_; ++n) {
          float2 pw = pw_l[t*N_ + n];
          pv += pw.x * stck[n];
          stck[n] += pw.y * (xi_c - stck[n]);
        }
        PV[(size_t)(b*T_ + t)*E_ + e] = pv;
        xi_c = xi_n;
      }
    }
    __threadfence_block();
    __syncthreads();
    for (int rl = wave*32; rl < wave*32 + 32; ++rl) {   // phase D: pv normalize
      int R = b*T_ + rl;
      float a = PV[(size_t)R*E_ + lane];
      float c = PV[(size_t)R*E_ + 64 + lane];
      float ss = a*a + c*c;
      #pragma unroll
      for (int off = 32; off >= 1; off >>= 1) ss += __shfl_xor(ss, off);
      float inv = 1.f / fmaxf(sqrtf(ss), 1e-8f);
      PVNb[(size_t)R*E_ + lane]      = f2bf_u(a*inv);
      PVNb[(size_t)R*E_ + 64 + lane] = f2bf_u(c*inv);
    }
    return;
  }

  // ---- tile path: 256(M) x 64(N), 4 waves x 4 m-tiles, A per-ks from global ----
  ushort* Bs = (ushort*)smem;
  const int Cb = blockIdx.x*64;
  {
    const uint4* srcB = (const uint4*)(Wfcb + (size_t)Cb*H_);
    #pragma unroll
    for (int it = 0; it < 8; ++it) {
      int idx = it*256 + tid, row = idx >> 5, c = idx & 31;
      *(uint4*)&Bs[row*PIT + c*8] = srcB[row*32 + c];
    }
  }
  const int Rw = (blockIdx.y - 1)*256 + wave*64;
  __syncthreads();
  f32x4 acc[4][4] = {};
  #pragma unroll
  for (int ks = 0; ks < 8; ++ks) {
    short8 a0 = *(const short8*)(HMb + (size_t)(Rw + 0*16 + lr)*H_ + ks*32 + g*8);
    short8 a1 = *(const short8*)(HMb + (size_t)(Rw + 1*16 + lr)*H_ + ks*32 + g*8);
    short8 a2 = *(const short8*)(HMb + (size_t)(Rw + 2*16 + lr)*H_ + ks*32 + g*8);
    short8 a3 = *(const short8*)(HMb + (size_t)(Rw + 3*16 + lr)*H_ + ks*32 + g*8);
    short8 b0 = *(const short8*)(&Bs[(0*16 + lr)*PIT + ks*32 + g*8]);
    short8 b1 = *(const short8*)(&Bs[(1*16 + lr)*PIT + ks*32 + g*8]);
    short8 b2 = *(const short8*)(&Bs[(2*16 + lr)*PIT + ks*32 + g*8]);
    short8 b3 = *(const short8*)(&Bs[(3*16 + lr)*PIT + ks*32 + g*8]);
    #define MF(mi, av) \
      acc[mi][0] = __builtin_amdgcn_mfma_f32_16x16x32_bf16(av, b0, acc[mi][0], 0, 0, 0); \
      acc[mi][1] = __builtin_amdgcn_mfma_f32_16x16x32_bf16(av, b1, acc[mi][1], 0, 0, 0); \
      acc[mi][2] = __builtin_amdgcn_mfma_f32_16x16x32_bf16(av, b2, acc[mi][2], 0, 0, 0); \
      acc[mi][3] = __builtin_amdgcn_mfma_f32_16x16x32_bf16(av, b3, acc[mi][3], 0, 0, 0);
    MF(0, a0) MF(1, a1) MF(2, a2) MF(3, a3)
    #undef MF
  }
  #pragma unroll
  for (int mi = 0; mi < 4; ++mi)
    #pragma unroll
    for (int r = 0; r < 4; ++r) {
      float s = expf(acc[mi][0][r]) + expf(acc[mi][1][r])
              + expf(acc[mi][2][r]) + expf(acc[mi][3][r]);
      #pragma unroll
      for (int off = 1; off < 16; off <<= 1) s += __shfl_xor(s, off);
      if (lr == 0) SS[(size_t)blockIdx.x*M_ + (Rw + mi*16 + g*4 + r)] = s;
    }
}

// ---------- combine chunk sums (SS transposed [chunk][row]) ----------
__global__ void reduce5_k(const float* __restrict__ SS, float* __restrict__ MS) {
  int row = blockIdx.x, l = threadIdx.x;  // 64 threads
  float s = 0.f;
  for (int c = l; c < NCH5; c += 64) s += SS[(size_t)c*M_ + row];
  #pragma unroll
  for (int off = 32; off >= 1; off >>= 1) s += __shfl_xor(s, off);
  if (l == 0) MS[row] = 1.f/s;
}

// ========== pass B: M=256 x N=64, logits recompute + syntactic, store fp32 ==========
__global__ __launch_bounds__(256) void final6_k(const ushort* __restrict__ HMb,
    const ushort* __restrict__ Wfcb, const ushort* __restrict__ PVNb,
    const ushort* __restrict__ embnb, const float* __restrict__ MS,
    const float* __restrict__ CH, float* __restrict__ out)
{
  __shared__ __align__(16) ushort Bs[64*PIT];     // 33.8 KB
  const int tid = threadIdx.x;
  const int Cb = blockIdx.x*64;
  const int wave = tid >> 6, lane = tid & 63;
  const int lr = lane & 15, g = lane >> 4;
  const int Rw = blockIdx.y*256 + wave*64;

  // logits (identical op sequence to stats6 -> bitwise-same)
  {
    const uint4* srcB = (const uint4*)(Wfcb + (size_t)Cb*H_);
    #pragma unroll
    for (int it = 0; it < 8; ++it) {
      int idx = it*256 + tid, row = idx >> 5, c = idx & 31;
      *(uint4*)&Bs[row*PIT + c*8] = srcB[row*32 + c];
    }
  }
  __syncthreads();
  f32x4 accL[4][4] = {};
  #pragma unroll
  for (int ks = 0; ks < 8; ++ks) {
    short8 a0 = *(const short8*)(HMb + (size_t)(Rw + 0*16 + lr)*H_ + ks*32 + g*8);
    short8 a1 = *(const short8*)(HMb + (size_t)(Rw + 1*16 + lr)*H_ + ks*32 + g*8);
    short8 a2 = *(const short8*)(HMb + (size_t)(Rw + 2*16 + lr)*H_ + ks*32 + g*8);
    short8 a3 = *(const short8*)(HMb + (size_t)(Rw + 3*16 + lr)*H_ + ks*32 + g*8);
    short8 b0 = *(const short8*)(&Bs[(0*16 + lr)*PIT + ks*32 + g*8]);
    short8 b1 = *(const short8*)(&Bs[(1*16 + lr)*PIT + ks*32 + g*8]);
    short8 b2 = *(const short8*)(&Bs[(2*16 + lr)*PIT + ks*32 + g*8]);
    short8 b3 = *(const short8*)(&Bs[(3*16 + lr)*PIT + ks*32 + g*8]);
    #define MFL(mi, av) \
      accL[mi][0] = __builtin_amdgcn_mfma_f32_16x16x32_bf16(av, b0, accL[mi][0], 0, 0, 0); \
      accL[mi][1] = __builtin_amdgcn_mfma_f32_16x16x32_bf16(av, b1, accL[mi][1], 0, 0, 0); \
      accL[mi][2] = __builtin_amdgcn_mfma_f32_16x16x32_bf16(av, b2, accL[mi][2], 0, 0, 0); \
      accL[mi][3] = __builtin_amdgcn_mfma_f32_16x16x32_bf16(av, b3, accL[mi][3], 0, 0, 0);
    MFL(0, a0) MFL(1, a1) MFL(2, a2) MFL(3, a3)
    #undef MFL
  }
  __syncthreads();   // all waves done reading logits B

  // syntactic K=128
  {
    const uint4* srcB = (const uint4*)(embnb + (size_t)Cb*E_);
    #pragma unroll
    for (int it = 0; it < 4; ++it) {
      int idx = it*256 + tid, row = idx >> 4, c = idx & 15;
      *(uint4*)&Bs[row*PIT2 + c*8] = srcB[row*16 + c];
    }
  }
  __syncthreads();
  f32x4 accS[4][4] = {};
  #pragma unroll
  for (int ks = 0; ks < 4; ++ks) {
    short8 a0 = *(const short8*)(PVNb + (size_t)(Rw + 0*16 + lr)*E_ + ks*32 + g*8);
    short8 a1 = *(const short8*)(PVNb + (size_t)(Rw + 1*16 + lr)*E_ + ks*32 + g*8);
    short8 a2 = *(const short8*)(PVNb + (size_t)(Rw + 2*16 + lr)*E_ + ks*32 + g*8);
    short8 a3 = *(const short8*)(PVNb + (size_t)(Rw + 3*16 + lr)*E_ + ks*32 + g*8);
    short8 b0 = *(const short8*)(&Bs[(0*16 + lr)*PIT2 + ks*32 + g*8]);
    short8 b1 = *(const short8*)(&Bs[(1*16 + lr)*PIT2 + ks*32 + g*8]);
    short8 b2 = *(const short8*)(&Bs[(2*16 + lr)*PIT2 + ks*32 + g*8]);
    short8 b3 = *(const short8*)(&Bs[(3*16 + lr)*PIT2 + ks*32 + g*8]);
    #define MFS(mi, av) \
      accS[mi][0] = __builtin_amdgcn_mfma_f32_16x16x32_bf16(av, b0, accS[mi][0], 0, 0, 0); \
      accS[mi][1] = __builtin_amdgcn_mfma_f32_16x16x32_bf16(av, b1, accS[mi][1], 0, 0, 0); \
      accS[mi][2] = __builtin_amdgcn_mfma_f32_16x16x32_bf16(av, b2, accS[mi][2], 0, 0, 0); \
      accS[mi][3] = __builtin_amdgcn_mfma_f32_16x16x32_bf16(av, b3, accS[mi][3], 0, 0, 0);
    MFS(0, a0) MFS(1, a1) MFS(2, a2) MFS(3, a3)
    #undef MFS
  }

  #pragma unroll
  for (int mi = 0; mi < 4; ++mi)
    #pragma unroll
    for (int r = 0; r < 4; ++r) {
      int row = Rw + mi*16 + g*4 + r;
      float Si = MS[row];
      float c0 = CH[row*2], c1 = CH[row*2+1];
      size_t base = (size_t)row*V_ + Cb + lr;
      #pragma unroll
      for (int nj = 0; nj < 4; ++nj)
        out[base + nj*16] = c0*expf(accL[mi][nj][r])*Si + c1*accS[mi][nj][r];
    }
}

extern "C" void kernel_launch(void* const* d_in, const int* in_sizes, int n_in,
                              void* d_out, int out_size, void* d_ws, size_t ws_size,
                              hipStream_t stream) {
  const int*   x_ids = (const int*)d_in[0];
  const float* emb   = (const float*)d_in[1];
  const float* W_i   = (const float*)d_in[2];
  const float* W_h   = (const float*)d_in[3];
  const float* W_fc  = (const float*)d_in[4];
  const float* W_ops = (const float*)d_in[5];
  const float* W_ch  = (const float*)d_in[6];
  const float* sharp = (const float*)d_in[7];
  float* out = (float*)d_out;

  float* ws    = (float*)d_ws;             // ~31 MB total
  uint4*  whb4 = (uint4*)ws;               // 8192 uint4 = 32768 floats
  float*  WiT  = ws + 65536;               // 32768
  float*  RI   = WiT + 32768;              // 262144
  float*  CH   = RI + 262144;              // 2048
  float*  MS   = CH + 2048;                // 1024
  float*  SS   = MS + 1024;                // 512,000 (transposed [chunk][row])
  float*  HMf  = SS + 512000;              // 262144
  float*  PV   = HMf + 262144;             // 131072
  float*  fend = PV + 131072;
  ushort* HMb   = (ushort*)fend;           // 262144 shorts
  ushort* PVNb  = HMb + 262144;            // 131072
  ushort* Wfcb  = PVNb + 131072;           // 8,192,000
  ushort* embnb = Wfcb + 8192000;          // 4,096,000

  prep_k <<<160, 256, 0, stream>>>(W_h, whb4, W_i, WiT);
  ri_k   <<<M_, 256, 0, stream>>>(x_ids, emb, WiT, RI);
  chain_k<<<248, 1024, 0, stream>>>(whb4, RI, HMf, HMb, W_fc, emb, Wfcb, embnb);
  stats6_k<<<dim3(NCH5, 5), 256, 0, stream>>>(HMb, Wfcb, HMf, W_ops, W_ch, sharp,
                                              x_ids, emb, SS, CH, PV, PVNb);
  reduce5_k<<<M_, 64, 0, stream>>>(SS, MS);
  final6_k<<<dim3(NCH5, M_/256), 256, 0, stream>>>(HMb, Wfcb, PVNb, embnb, MS, CH, out);
}